// Round 1
// baseline (434.763 us; speedup 1.0000x reference)
//
#include <hip/hip_runtime.h>

// ---------------------------------------------------------------- types
typedef __bf16 bf16_t;
typedef bf16_t bf16x8 __attribute__((ext_vector_type(8)));
typedef float f32x4 __attribute__((ext_vector_type(4)));

#define S_LEN 2048
#define NHEAD 16
#define DHEAD 64
#define DMODEL 1024
#define BATCH 2

__device__ __forceinline__ float bf2f(unsigned short u) {
    unsigned int x = ((unsigned int)u) << 16;
    return __builtin_bit_cast(float, x);
}
__device__ __forceinline__ unsigned short f2bf(float f) {
    unsigned int x = __builtin_bit_cast(unsigned int, f);
    x += 0x7fffu + ((x >> 16) & 1u);          // RNE
    return (unsigned short)(x >> 16);
}

// ---------------------------------------------------------------- GEMM
// C[M][N] = A[M][K] * B[N][K]^T + bias
// A: fp32 (A_BF16=false) or bf16 (A_BF16=true), row-major [M][K]
// B: fp32 row-major [N][K]  (i.e. W, since y = x @ W.T)
// EPI: 0 = fp32 out row-major [M][N]
//      1 = bf16 out row-major [M][N]
//      2 = bf16 out scattered to [B,H,S,Dh]  (row=b*S+s, col=h*64+d)
#define LDSTRIDE 56   // 32 payload + 24 pad; 112B row = 7*16B, 2-way bank alias only

template<bool A_BF16, int EPI>
__global__ __launch_bounds__(256) void gemm_bt_kernel(
    const void* __restrict__ Ap, const float* __restrict__ Bw,
    const float* __restrict__ bias, void* __restrict__ Cp,
    int M, int N, int K)
{
    __shared__ __align__(16) unsigned short As[128 * LDSTRIDE];
    __shared__ __align__(16) unsigned short Bs[128 * LDSTRIDE];

    const int tid  = threadIdx.x;
    const int lane = tid & 63;
    const int w    = tid >> 6;
    const int quad = lane >> 4;
    const int l16  = lane & 15;
    const int wm   = (w >> 1) * 64;
    const int wn   = (w & 1) * 64;
    const int bm   = blockIdx.y * 128;
    const int bn   = blockIdx.x * 128;

    f32x4 acc[4][4];
#pragma unroll
    for (int i = 0; i < 4; ++i)
#pragma unroll
        for (int j = 0; j < 4; ++j)
            acc[i][j] = f32x4{0.f, 0.f, 0.f, 0.f};

    const int r_st = tid >> 1;          // 0..127 (tile row)
    const int h_st = (tid & 1) * 16;    // 0 or 16 (col offset)

    for (int k0 = 0; k0 < K; k0 += 32) {
        __syncthreads();
        // ---- stage A tile (convert fp32->bf16 if needed)
        if constexpr (A_BF16) {
            const unsigned short* A16 = (const unsigned short*)Ap;
#pragma unroll
            for (int j = 0; j < 4; ++j) {
                uint2 v = *(const uint2*)(A16 + (size_t)(bm + r_st) * K + k0 + h_st + j * 4);
                *(uint2*)(&As[r_st * LDSTRIDE + h_st + j * 4]) = v;
            }
        } else {
            const float* Af = (const float*)Ap;
#pragma unroll
            for (int j = 0; j < 4; ++j) {
                float4 v = *(const float4*)(Af + (size_t)(bm + r_st) * K + k0 + h_st + j * 4);
                ushort4 o;
                o.x = f2bf(v.x); o.y = f2bf(v.y); o.z = f2bf(v.z); o.w = f2bf(v.w);
                *(ushort4*)(&As[r_st * LDSTRIDE + h_st + j * 4]) = o;
            }
        }
        // ---- stage B tile (always fp32 weights)
#pragma unroll
        for (int j = 0; j < 4; ++j) {
            float4 v = *(const float4*)(Bw + (size_t)(bn + r_st) * K + k0 + h_st + j * 4);
            ushort4 o;
            o.x = f2bf(v.x); o.y = f2bf(v.y); o.z = f2bf(v.z); o.w = f2bf(v.w);
            *(ushort4*)(&Bs[r_st * LDSTRIDE + h_st + j * 4]) = o;
        }
        __syncthreads();

        bf16x8 aF[4], bF[4];
#pragma unroll
        for (int t = 0; t < 4; ++t) {
            aF[t] = *(const bf16x8*)(&As[(wm + t * 16 + l16) * LDSTRIDE + quad * 8]);
            bF[t] = *(const bf16x8*)(&Bs[(wn + t * 16 + l16) * LDSTRIDE + quad * 8]);
        }
#pragma unroll
        for (int mt = 0; mt < 4; ++mt)
#pragma unroll
            for (int nt = 0; nt < 4; ++nt)
                acc[mt][nt] = __builtin_amdgcn_mfma_f32_16x16x32_bf16(
                    aF[mt], bF[nt], acc[mt][nt], 0, 0, 0);
    }

    // ---- epilogue
#pragma unroll
    for (int mt = 0; mt < 4; ++mt) {
        const int row0 = bm + wm + mt * 16 + quad * 4;
#pragma unroll
        for (int nt = 0; nt < 4; ++nt) {
            const int col = bn + wn + nt * 16 + l16;
            const float bv = bias[col];
#pragma unroll
            for (int r = 0; r < 4; ++r) {
                const float val = acc[mt][nt][r] + bv;
                const int row = row0 + r;
                if constexpr (EPI == 0) {
                    ((float*)Cp)[(size_t)row * N + col] = val;
                } else if constexpr (EPI == 1) {
                    ((unsigned short*)Cp)[(size_t)row * N + col] = f2bf(val);
                } else {
                    const int b = row >> 11, s = row & (S_LEN - 1);
                    const int h = col >> 6, d = col & (DHEAD - 1);
                    ((unsigned short*)Cp)[(((size_t)(b * NHEAD + h)) * S_LEN + s) * DHEAD + d] = f2bf(val);
                }
            }
        }
    }
}

// ---------------------------------------------------------------- RoPE
// in : Y [B,S,D] bf16 (raw projection)   out : [B,H,S,Dh] bf16 with RoPE
__global__ __launch_bounds__(256) void rope_kernel(
    const unsigned short* __restrict__ Yq, const unsigned short* __restrict__ Yk,
    unsigned short* __restrict__ Qo, unsigned short* __restrict__ Ko)
{
    const int idx = blockIdx.x * 256 + threadIdx.x;   // [0, B*S*H*32)
    const unsigned short* Y = blockIdx.y ? Yk : Yq;
    unsigned short* O = blockIdx.y ? Ko : Qo;

    const int d = idx & 31;
    int t = idx >> 5;
    const int h = t & (NHEAD - 1);
    t >>= 4;
    const int s = t & (S_LEN - 1);
    const int b = t >> 11;

    const size_t ibase = ((size_t)(b * S_LEN + s)) * DMODEL + h * DHEAD + d;
    const float x1 = bf2f(Y[ibase]);
    const float x2 = bf2f(Y[ibase + 32]);

    const float freq = powf(10000.f, -(float)d * (1.f / 32.f));
    const float ang  = (float)s * freq;
    const float c = cosf(ang), sn = sinf(ang);
    const float o1 = x1 * c - x2 * sn;
    const float o2 = x2 * c + x1 * sn;

    const size_t obase = (((size_t)(b * NHEAD + h)) * S_LEN + s) * DHEAD + d;
    O[obase]      = f2bf(o1);
    O[obase + 32] = f2bf(o2);
}

// ---------------------------------------------------------------- attention
// Q,K,V: [B,H,S,Dh] bf16.  Out: [B,S,H*Dh] bf16.
// Block: 256 thr = 4 waves; 64 Q-rows per block (16/wave). Flash-style causal.
#define KSTR 72   // 64 payload + 8 pad; 144B row = 9*16B, 2-way bank alias only

__global__ __launch_bounds__(256) void attn_kernel(
    const unsigned short* __restrict__ Q, const unsigned short* __restrict__ K,
    const unsigned short* __restrict__ V, unsigned short* __restrict__ O)
{
    const int qt = blockIdx.x;           // q-tile (64 rows)
    const int h  = blockIdx.y;
    const int b  = blockIdx.z;
    const int tid  = threadIdx.x;
    const int w    = tid >> 6;
    const int lane = tid & 63;
    const int quad = lane >> 4;
    const int l16  = lane & 15;

    __shared__ __align__(16) unsigned short Ks[64 * KSTR];
    __shared__ __align__(16) unsigned short Vt[64 * KSTR];   // transposed: [dh][seq]
    __shared__ __align__(16) unsigned short Pb[4][16 * KSTR];

    const int q0 = qt * 64;
    const size_t headoff = ((size_t)(b * NHEAD + h)) * S_LEN * DHEAD;
    const unsigned short* Qh = Q + headoff;
    const unsigned short* Kh = K + headoff;
    const unsigned short* Vh = V + headoff;

    // Q fragments (A-layout), held in registers for the whole block
    const int qrow = q0 + w * 16 + l16;
    const bf16x8 qf0 = *(const bf16x8*)(Qh + (size_t)qrow * DHEAD + quad * 8);
    const bf16x8 qf1 = *(const bf16x8*)(Qh + (size_t)qrow * DHEAD + 32 + quad * 8);

    f32x4 o[4];
#pragma unroll
    for (int i = 0; i < 4; ++i) o[i] = f32x4{0.f, 0.f, 0.f, 0.f};
    float m_i[4], l_i[4];
#pragma unroll
    for (int r = 0; r < 4; ++r) { m_i[r] = -INFINITY; l_i[r] = 0.f; }

    const int nkt = qt + 1;
    for (int kt = 0; kt < nkt; ++kt) {
        __syncthreads();
        // ---- stage K tile (row-major) and V tile (transposed)
        {
            const int base = kt * 64;
#pragma unroll
            for (int it = 0; it < 2; ++it) {
                const int idx = tid * 2 + it;
                const int r  = idx >> 3;
                const int c8 = idx & 7;
                uint4 kv = *(const uint4*)(Kh + (size_t)(base + r) * DHEAD + c8 * 8);
                *(uint4*)(&Ks[r * KSTR + c8 * 8]) = kv;
                union { uint4 u; unsigned short s[8]; } uv;
                uv.u = *(const uint4*)(Vh + (size_t)(base + r) * DHEAD + c8 * 8);
#pragma unroll
                for (int j = 0; j < 8; ++j)
                    Vt[(c8 * 8 + j) * KSTR + r] = uv.s[j];
            }
        }
        __syncthreads();

        // ---- scores: S = Q K^T * scale  (16x64 per wave)
        f32x4 sc[4];
#pragma unroll
        for (int nt = 0; nt < 4; ++nt) {
            const bf16x8 kf0 = *(const bf16x8*)(&Ks[(nt * 16 + l16) * KSTR + quad * 8]);
            const bf16x8 kf1 = *(const bf16x8*)(&Ks[(nt * 16 + l16) * KSTR + 32 + quad * 8]);
            f32x4 a = f32x4{0.f, 0.f, 0.f, 0.f};
            a = __builtin_amdgcn_mfma_f32_16x16x32_bf16(qf0, kf0, a, 0, 0, 0);
            a = __builtin_amdgcn_mfma_f32_16x16x32_bf16(qf1, kf1, a, 0, 0, 0);
            sc[nt] = a;
        }
        const int qpos0 = q0 + w * 16 + quad * 4;
#pragma unroll
        for (int nt = 0; nt < 4; ++nt)
#pragma unroll
            for (int r = 0; r < 4; ++r)
                sc[nt][r] *= 0.125f;
        if (kt == qt) {   // diagonal tile: causal mask
#pragma unroll
            for (int nt = 0; nt < 4; ++nt) {
                const int kpos = kt * 64 + nt * 16 + l16;
#pragma unroll
                for (int r = 0; r < 4; ++r)
                    if (kpos > qpos0 + r) sc[nt][r] = -INFINITY;
            }
        }

        // ---- online softmax (rows live in 16-lane quad groups)
        float alpha[4], mnew[4];
#pragma unroll
        for (int r = 0; r < 4; ++r) {
            float mx = fmaxf(fmaxf(sc[0][r], sc[1][r]), fmaxf(sc[2][r], sc[3][r]));
#pragma unroll
            for (int msk = 1; msk < 16; msk <<= 1)
                mx = fmaxf(mx, __shfl_xor(mx, msk));
            mnew[r]  = fmaxf(m_i[r], mx);
            alpha[r] = __expf(m_i[r] - mnew[r]);
            m_i[r]   = mnew[r];
        }
#pragma unroll
        for (int nt = 0; nt < 4; ++nt)
#pragma unroll
            for (int r = 0; r < 4; ++r)
                sc[nt][r] = __expf(sc[nt][r] - mnew[r]);
#pragma unroll
        for (int r = 0; r < 4; ++r) {
            float rs = sc[0][r] + sc[1][r] + sc[2][r] + sc[3][r];
#pragma unroll
            for (int msk = 1; msk < 16; msk <<= 1)
                rs += __shfl_xor(rs, msk);
            l_i[r] = l_i[r] * alpha[r] + rs;
        }
        // rescale O
#pragma unroll
        for (int nt = 0; nt < 4; ++nt)
#pragma unroll
            for (int r = 0; r < 4; ++r)
                o[nt][r] *= alpha[r];

        // ---- P: C-layout regs -> LDS -> A-layout frags
#pragma unroll
        for (int nt = 0; nt < 4; ++nt)
#pragma unroll
            for (int r = 0; r < 4; ++r)
                Pb[w][(quad * 4 + r) * KSTR + nt * 16 + l16] = f2bf(sc[nt][r]);
        __syncthreads();

        const bf16x8 pA0 = *(const bf16x8*)(&Pb[w][l16 * KSTR + quad * 8]);
        const bf16x8 pA1 = *(const bf16x8*)(&Pb[w][l16 * KSTR + 32 + quad * 8]);
#pragma unroll
        for (int nt = 0; nt < 4; ++nt) {
            const bf16x8 v0 = *(const bf16x8*)(&Vt[(nt * 16 + l16) * KSTR + quad * 8]);
            const bf16x8 v1 = *(const bf16x8*)(&Vt[(nt * 16 + l16) * KSTR + 32 + quad * 8]);
            o[nt] = __builtin_amdgcn_mfma_f32_16x16x32_bf16(pA0, v0, o[nt], 0, 0, 0);
            o[nt] = __builtin_amdgcn_mfma_f32_16x16x32_bf16(pA1, v1, o[nt], 0, 0, 0);
        }
    }

    // ---- epilogue: O /= l, write [B,S,H*Dh]
    float linv[4];
#pragma unroll
    for (int r = 0; r < 4; ++r) linv[r] = 1.0f / l_i[r];
    const int spos0 = q0 + w * 16 + quad * 4;
#pragma unroll
    for (int nt = 0; nt < 4; ++nt)
#pragma unroll
        for (int r = 0; r < 4; ++r) {
            const float val = o[nt][r] * linv[r];
            O[((size_t)(b) * S_LEN + spos0 + r) * DMODEL + h * DHEAD + nt * 16 + l16] = f2bf(val);
        }
}

// ---------------------------------------------------------------- launch
extern "C" void kernel_launch(void* const* d_in, const int* in_sizes, int n_in,
                              void* d_out, int out_size, void* d_ws, size_t ws_size,
                              hipStream_t stream) {
    const float* x  = (const float*)d_in[0];
    const float* Wq = (const float*)d_in[1];
    const float* bq = (const float*)d_in[2];
    const float* Wk = (const float*)d_in[3];
    const float* bk = (const float*)d_in[4];
    const float* Wv = (const float*)d_in[5];
    const float* bv = (const float*)d_in[6];
    const float* Wo = (const float*)d_in[7];
    const float* bo = (const float*)d_in[8];
    float* out = (float*)d_out;

    char* ws = (char*)d_ws;
    const size_t SZ = (size_t)BATCH * S_LEN * DMODEL * sizeof(unsigned short); // 8 MB
    unsigned short* Yq = (unsigned short*)(ws);
    unsigned short* Yk = (unsigned short*)(ws + SZ);
    unsigned short* Qr = (unsigned short*)(ws + 2 * SZ);
    unsigned short* Kr = (unsigned short*)(ws + 3 * SZ);
    unsigned short* Vr = (unsigned short*)(ws + 4 * SZ);
    unsigned short* AO = (unsigned short*)(ws + 5 * SZ);

    const int M = BATCH * S_LEN;      // 4096
    const dim3 gg(DMODEL / 128, M / 128);   // (8, 32)

    gemm_bt_kernel<false, 1><<<gg, 256, 0, stream>>>(x, Wq, bq, Yq, M, DMODEL, DMODEL);
    gemm_bt_kernel<false, 1><<<gg, 256, 0, stream>>>(x, Wk, bk, Yk, M, DMODEL, DMODEL);
    gemm_bt_kernel<false, 2><<<gg, 256, 0, stream>>>(x, Wv, bv, Vr, M, DMODEL, DMODEL);

    rope_kernel<<<dim3((BATCH * S_LEN * NHEAD * 32) / 256, 2), 256, 0, stream>>>(Yq, Yk, Qr, Kr);

    attn_kernel<<<dim3(S_LEN / 64, NHEAD, BATCH), 256, 0, stream>>>(Qr, Kr, Vr, AO);

    gemm_bt_kernel<true, 0><<<gg, 256, 0, stream>>>(AO, Wo, bo, out, M, DMODEL, DMODEL);
}